// Round 5
// baseline (85.293 us; speedup 1.0000x reference)
//
#include <hip/hip_runtime.h>
#include <math.h>

#define BATCH 32
#define HQ 32
#define HKV 8
#define DHEAD 128
#define BS 16
#define MAXB 128
#define G 4              // HQ / HKV
#define CHUNK 128        // positions per chunk-block
#define MAXCH 16         // LMAX / CHUNK
#define NW 4             // waves per chunk block
#define NT (NW * 64)

#define NSLOT (BATCH * HKV * MAXCH)   // 4096
#define NBKV  (BATCH * HKV)           // 256

typedef float v2f __attribute__((ext_vector_type(2)));

__device__ __forceinline__ v2f pk_fma(v2f a, v2f b, v2f c) {
    v2f d;
    asm("v_pk_fma_f32 %0, %1, %2, %3" : "=v"(d) : "v"(a), "v"(b), "v"(c));
    return d;
}
__device__ __forceinline__ v2f pk_mul(v2f a, v2f b) {
    v2f d;
    asm("v_pk_mul_f32 %0, %1, %2" : "=v"(d) : "v"(a), "v"(b));
    return d;
}
__device__ __forceinline__ float fexp2(float x) {
    float r;
    asm("v_exp_f32 %0, %1" : "=v"(r) : "v"(x));
    return r;
}

// rotate-and-add over each 16-lane row, 4 independent chains.
#define ROR4(N, x0, x1, x2, x3)                                                   \
    asm("s_nop 1\n\t"                                                             \
        "v_add_f32_dpp %0, %0, %0 row_ror:" #N " row_mask:0xf bank_mask:0xf\n\t"  \
        "v_add_f32_dpp %1, %1, %1 row_ror:" #N " row_mask:0xf bank_mask:0xf\n\t"  \
        "v_add_f32_dpp %2, %2, %2 row_ror:" #N " row_mask:0xf bank_mask:0xf\n\t"  \
        "v_add_f32_dpp %3, %3, %3 row_ror:" #N " row_mask:0xf bank_mask:0xf"      \
        : "+v"(x0), "+v"(x1), "+v"(x2), "+v"(x3))

// ---------- prep: RoPE(q)*scale*log2e, RoPE(new_k), copy new_v ----------
__global__ __launch_bounds__(128) void paged_attn_prep(
    const float* __restrict__ query,
    const float* __restrict__ new_k,
    const float* __restrict__ new_v,
    const int*   __restrict__ context_lens,
    float* __restrict__ qs,   // [NBKV][G*DHEAD]
    float* __restrict__ kn,   // [NBKV][DHEAD]
    float* __restrict__ vn)   // [NBKV][DHEAD]
{
    const int bkv = blockIdx.x;
    const int kv  = bkv & 7;
    const int b   = bkv >> 3;
    const int tid = threadIdx.x;

    __shared__ float s_cos[64], s_sin[64];
    const int pos = context_lens[b];
    if (tid < 64) {
        float invf = exp2f((float)tid * -0.20762050593046014f); // 10000^(-tid/64)
        float ang  = (float)pos * invf;
        s_cos[tid] = cosf(ang);
        s_sin[tid] = sinf(ang);
    }
    __syncthreads();

    // 1/sqrt(128) * log2(e)  (so exp2 of the dot gives softmax weights)
    const float scale = 0.08838834764831845f * 1.4426950408889634f;

    for (int idx = tid; idx < G * DHEAD; idx += 128) {
        int h = idx >> 7, d = idx & 127;
        const float* qp = query + ((size_t)b * HQ + kv * G + h) * DHEAD;
        float x = qp[d], r;
        if (d < 64) r = x * s_cos[d]      - qp[d + 64] * s_sin[d];
        else        r = x * s_cos[d - 64] + qp[d - 64] * s_sin[d - 64];
        qs[(size_t)bkv * (G * DHEAD) + idx] = r * scale;
    }
    {
        int d = tid;
        const float* kp = new_k + ((size_t)b * HKV + kv) * DHEAD;
        float x = kp[d], r;
        if (d < 64) r = x * s_cos[d]      - kp[d + 64] * s_sin[d];
        else        r = x * s_cos[d - 64] + kp[d - 64] * s_sin[d - 64];
        kn[(size_t)bkv * DHEAD + d] = r;
        vn[(size_t)bkv * DHEAD + d] = new_v[((size_t)b * HKV + kv) * DHEAD + d];
    }
}

// ---------- main: one chunk of 128 positions per block ----------
__global__ __launch_bounds__(NT) void paged_attn_chunk(
    const float* __restrict__ k_cache,
    const float* __restrict__ v_cache,
    const int*   __restrict__ block_table,
    const int*   __restrict__ context_lens,
    const float* __restrict__ qs,
    const float* __restrict__ kn,
    const float* __restrict__ vn,
    float*       __restrict__ wsacc,   // [NSLOT][G*DHEAD]
    float*       __restrict__ wsl)     // [NSLOT][G]
{
    const int c   = blockIdx.x & (MAXCH - 1);
    const int bkv = blockIdx.x >> 4;
    const int kv  = bkv & 7;
    const int b   = bkv >> 3;

    const int pos = context_lens[b];
    const int c0  = c << 7;
    if (c0 > pos) return;              // chunk entirely beyond len

    const int tid  = threadIdx.x;
    const int w    = tid >> 6;
    const int lane = tid & 63;
    const int grp  = lane >> 4;
    const int sub  = lane & 15;

    __shared__ float s_wacc[NW][G][DHEAD];
    __shared__ float s_wl[NW][G];

    // q fragments (pre-roped, pre-scaled)
    v2f q2[G][4];
    const float* qb = qs + (size_t)bkv * (G * DHEAD) + sub * 8;
    #pragma unroll
    for (int h = 0; h < G; h++) {
        float4 qa = *(const float4*)(qb + h * DHEAD);
        float4 qc = *(const float4*)(qb + h * DHEAD + 4);
        q2[h][0] = v2f{qa.x, qa.y}; q2[h][1] = v2f{qa.z, qa.w};
        q2[h][2] = v2f{qc.x, qc.y}; q2[h][3] = v2f{qc.z, qc.w};
    }

    // the two cache blocks this wave touches (wave-uniform SGPRs)
    const int tb  = b * MAXB + (c0 >> 4) + w * 2;
    const int bt0 = __builtin_amdgcn_readfirstlane(block_table[tb]);
    const int bt1 = __builtin_amdgcn_readfirstlane(block_table[tb + 1]);

    // per-lane float offset inside a [16][HKV][128] cache block
    const int poff = grp * (HKV * DHEAD) + kv * DHEAD + sub * 8;
    const float* kb0 = k_cache + (size_t)bt0 * (BS * HKV * DHEAD) + poff;
    const float* kb1 = k_cache + (size_t)bt1 * (BS * HKV * DHEAD) + poff;
    const float* vb0 = v_cache + (size_t)bt0 * (BS * HKV * DHEAD) + poff;
    const float* vb1 = v_cache + (size_t)bt1 * (BS * HKV * DHEAD) + poff;

    const float* knp = kn + (size_t)bkv * DHEAD + sub * 8;
    const float* vnp = vn + (size_t)bkv * DHEAD + sub * 8;

    const int p0 = c0 + w * 32 + grp;  // position for (it, grp): p0 + it*4

    v2f acc2[G][4];
    float l[G];
    #pragma unroll
    for (int h = 0; h < G; h++) {
        l[h] = 0.f;
        #pragma unroll
        for (int j = 0; j < 4; j++) acc2[h][j] = v2f{0.f, 0.f};
    }

    float4 kaA, kbA, vaA, vbA;   // pipeline buffer A
    float4 kaB, kbB, vaB, vbB;   // pipeline buffer B

#define LOADSET(KA, KB, VA, VB, IT) do {                                       \
        const float* kp_ = ((IT) < 4 ? kb0 : kb1) + ((IT) & 3) * 4096;         \
        const float* vp_ = ((IT) < 4 ? vb0 : vb1) + ((IT) & 3) * 4096;         \
        KA = *(const float4*)kp_;  KB = *(const float4*)(kp_ + 4);             \
        VA = *(const float4*)vp_;  VB = *(const float4*)(vp_ + 4);             \
    } while (0)

#define COMPSET(KA, KB, VA, VB, IT) do {                                       \
        const int pi_ = p0 + (IT) * 4;                                         \
        if (__builtin_expect(pi_ == pos, 0)) {      /* new-token substitution */\
            KA = *(const float4*)(knp);  KB = *(const float4*)(knp + 4);       \
            VA = *(const float4*)(vnp);  VB = *(const float4*)(vnp + 4);       \
        }                                                                      \
        v2f k0_ = v2f{KA.x, KA.y}, k1_ = v2f{KA.z, KA.w};                      \
        v2f k2_ = v2f{KB.x, KB.y}, k3_ = v2f{KB.z, KB.w};                      \
        v2f d0_ = pk_fma(q2[0][3], k3_, pk_fma(q2[0][2], k2_,                  \
                  pk_fma(q2[0][1], k1_, pk_mul(q2[0][0], k0_))));              \
        v2f d1_ = pk_fma(q2[1][3], k3_, pk_fma(q2[1][2], k2_,                  \
                  pk_fma(q2[1][1], k1_, pk_mul(q2[1][0], k0_))));              \
        v2f d2_ = pk_fma(q2[2][3], k3_, pk_fma(q2[2][2], k2_,                  \
                  pk_fma(q2[2][1], k1_, pk_mul(q2[2][0], k0_))));              \
        v2f d3_ = pk_fma(q2[3][3], k3_, pk_fma(q2[3][2], k2_,                  \
                  pk_fma(q2[3][1], k1_, pk_mul(q2[3][0], k0_))));              \
        float dt0 = d0_.x + d0_.y, dt1 = d1_.x + d1_.y;                        \
        float dt2 = d2_.x + d2_.y, dt3 = d3_.x + d3_.y;                        \
        ROR4(8, dt0, dt1, dt2, dt3);                                           \
        ROR4(4, dt0, dt1, dt2, dt3);                                           \
        ROR4(2, dt0, dt1, dt2, dt3);                                           \
        ROR4(1, dt0, dt1, dt2, dt3);                                           \
        const bool act_ = pi_ <= pos;                                          \
        float wg0 = act_ ? fexp2(dt0) : 0.f;                                   \
        float wg1 = act_ ? fexp2(dt1) : 0.f;                                   \
        float wg2 = act_ ? fexp2(dt2) : 0.f;                                   \
        float wg3 = act_ ? fexp2(dt3) : 0.f;                                   \
        l[0] += wg0; l[1] += wg1; l[2] += wg2; l[3] += wg3;                    \
        v2f u0_ = v2f{VA.x, VA.y}, u1_ = v2f{VA.z, VA.w};                      \
        v2f u2_ = v2f{VB.x, VB.y}, u3_ = v2f{VB.z, VB.w};                      \
        v2f w0_ = v2f{wg0, wg0}, w1_ = v2f{wg1, wg1};                          \
        v2f w2_ = v2f{wg2, wg2}, w3_ = v2f{wg3, wg3};                          \
        acc2[0][0] = pk_fma(w0_, u0_, acc2[0][0]);                             \
        acc2[0][1] = pk_fma(w0_, u1_, acc2[0][1]);                             \
        acc2[0][2] = pk_fma(w0_, u2_, acc2[0][2]);                             \
        acc2[0][3] = pk_fma(w0_, u3_, acc2[0][3]);                             \
        acc2[1][0] = pk_fma(w1_, u0_, acc2[1][0]);                             \
        acc2[1][1] = pk_fma(w1_, u1_, acc2[1][1]);                             \
        acc2[1][2] = pk_fma(w1_, u2_, acc2[1][2]);                             \
        acc2[1][3] = pk_fma(w1_, u3_, acc2[1][3]);                             \
        acc2[2][0] = pk_fma(w2_, u0_, acc2[2][0]);                             \
        acc2[2][1] = pk_fma(w2_, u1_, acc2[2][1]);                             \
        acc2[2][2] = pk_fma(w2_, u2_, acc2[2][2]);                             \
        acc2[2][3] = pk_fma(w2_, u3_, acc2[2][3]);                             \
        acc2[3][0] = pk_fma(w3_, u0_, acc2[3][0]);                             \
        acc2[3][1] = pk_fma(w3_, u1_, acc2[3][1]);                             \
        acc2[3][2] = pk_fma(w3_, u2_, acc2[3][2]);                             \
        acc2[3][3] = pk_fma(w3_, u3_, acc2[3][3]);                             \
    } while (0)

    // depth-2 software pipeline over 8 compile-time iterations
    LOADSET(kaA, kbA, vaA, vbA, 0);
    LOADSET(kaB, kbB, vaB, vbB, 1);
    COMPSET(kaA, kbA, vaA, vbA, 0);  LOADSET(kaA, kbA, vaA, vbA, 2);
    COMPSET(kaB, kbB, vaB, vbB, 1);  LOADSET(kaB, kbB, vaB, vbB, 3);
    COMPSET(kaA, kbA, vaA, vbA, 2);  LOADSET(kaA, kbA, vaA, vbA, 4);
    COMPSET(kaB, kbB, vaB, vbB, 3);  LOADSET(kaB, kbB, vaB, vbB, 5);
    COMPSET(kaA, kbA, vaA, vbA, 4);  LOADSET(kaA, kbA, vaA, vbA, 6);
    COMPSET(kaB, kbB, vaB, vbB, 5);  LOADSET(kaB, kbB, vaB, vbB, 7);
    COMPSET(kaA, kbA, vaA, vbA, 6);
    COMPSET(kaB, kbB, vaB, vbB, 7);

#undef LOADSET
#undef COMPSET

    // ---- reduce across the 4 groups ----
    #pragma unroll
    for (int h = 0; h < G; h++) {
        l[h] += __shfl_xor(l[h], 16, 64);
        l[h] += __shfl_xor(l[h], 32, 64);
        #pragma unroll
        for (int j = 0; j < 4; j++) {
            float ax = acc2[h][j].x, ay = acc2[h][j].y;
            ax += __shfl_xor(ax, 16, 64); ax += __shfl_xor(ax, 32, 64);
            ay += __shfl_xor(ay, 16, 64); ay += __shfl_xor(ay, 32, 64);
            acc2[h][j] = v2f{ax, ay};
        }
    }
    if (lane < 16) {
        #pragma unroll
        for (int h = 0; h < G; h++)
            #pragma unroll
            for (int j = 0; j < 4; j++) {
                s_wacc[w][h][sub * 8 + 2 * j]     = acc2[h][j].x;
                s_wacc[w][h][sub * 8 + 2 * j + 1] = acc2[h][j].y;
            }
    }
    if (lane == 0) {
        #pragma unroll
        for (int h = 0; h < G; h++) s_wl[w][h] = l[h];
    }
    __syncthreads();

    const size_t slot_base = (size_t)blockIdx.x * (G * DHEAD);
    for (int idx = tid; idx < G * DHEAD; idx += NT) {
        float s = s_wacc[0][idx >> 7][idx & 127] + s_wacc[1][idx >> 7][idx & 127]
                + s_wacc[2][idx >> 7][idx & 127] + s_wacc[3][idx >> 7][idx & 127];
        wsacc[slot_base + idx] = s;
    }
    if (tid < G) {
        wsl[(size_t)blockIdx.x * G + tid] =
            s_wl[0][tid] + s_wl[1][tid] + s_wl[2][tid] + s_wl[3][tid];
    }
}

__global__ __launch_bounds__(512) void paged_attn_combine(
    const int*   __restrict__ context_lens,
    const float* __restrict__ wsacc,
    const float* __restrict__ wsl,
    float*       __restrict__ out)
{
    const int bkv = blockIdx.x;
    const int kv  = bkv & 7;
    const int b   = bkv >> 3;
    const int t   = threadIdx.x;
    const int h   = t >> 7;
    const int d   = t & 127;

    const int len = context_lens[b] + 1;
    const int nch = (len + CHUNK - 1) >> 7;

    float asum = 0.f, lsum = 0.f;
    for (int cc = 0; cc < nch; cc++) {
        asum += wsacc[((size_t)bkv * MAXCH + cc) * (G * DHEAD) + t];
        lsum += wsl[((size_t)bkv * MAXCH + cc) * G + h];
    }
    out[((size_t)b * HQ + kv * G + h) * DHEAD + d] = asum / lsum;
}

extern "C" void kernel_launch(void* const* d_in, const int* in_sizes, int n_in,
                              void* d_out, int out_size, void* d_ws, size_t ws_size,
                              hipStream_t stream) {
    const float* query        = (const float*)d_in[0];
    const float* new_k        = (const float*)d_in[1];
    const float* new_v        = (const float*)d_in[2];
    const float* k_cache      = (const float*)d_in[3];
    const float* v_cache      = (const float*)d_in[4];
    const int*   block_table  = (const int*)d_in[5];
    const int*   context_lens = (const int*)d_in[6];
    float* out = (float*)d_out;

    float* wsacc = (float*)d_ws;                          // NSLOT*512
    float* wsl   = wsacc + (size_t)NSLOT * G * DHEAD;     // NSLOT*4
    float* qs    = wsl + (size_t)NSLOT * G;               // NBKV*512
    float* kn    = qs + (size_t)NBKV * G * DHEAD;         // NBKV*128
    float* vn    = kn + (size_t)NBKV * DHEAD;             // NBKV*128

    paged_attn_prep<<<dim3(NBKV), dim3(128), 0, stream>>>(
        query, new_k, new_v, context_lens, qs, kn, vn);
    paged_attn_chunk<<<dim3(NSLOT), dim3(NT), 0, stream>>>(
        k_cache, v_cache, block_table, context_lens, qs, kn, vn, wsacc, wsl);
    paged_attn_combine<<<dim3(NBKV), dim3(512), 0, stream>>>(
        context_lens, wsacc, wsl, out);
}

// Round 6
// 79.722 us; speedup vs baseline: 1.0699x; 1.0699x over previous
//
#include <hip/hip_runtime.h>
#include <math.h>

#define BATCH 32
#define HQ 32
#define HKV 8
#define DHEAD 128
#define BS 16
#define MAXB 128
#define G 4              // HQ / HKV
#define CHUNK 256        // positions per chunk-block
#define MAXCH 8          // LMAX / CHUNK
#define NW 4             // waves per chunk block
#define NT (NW * 64)

#define NSLOT (BATCH * HKV * MAXCH)   // 2048
#define NBKV  (BATCH * HKV)           // 256

typedef float v2f __attribute__((ext_vector_type(2)));

__device__ __forceinline__ v2f pk_fma(v2f a, v2f b, v2f c) {
    v2f d;
    asm("v_pk_fma_f32 %0, %1, %2, %3" : "=v"(d) : "v"(a), "v"(b), "v"(c));
    return d;
}
__device__ __forceinline__ v2f pk_mul(v2f a, v2f b) {
    v2f d;
    asm("v_pk_mul_f32 %0, %1, %2" : "=v"(d) : "v"(a), "v"(b));
    return d;
}
__device__ __forceinline__ float fexp2(float x) {
    float r;
    asm("v_exp_f32 %0, %1" : "=v"(r) : "v"(x));
    return r;
}

// rotate-and-add over each 16-lane row, 4 independent chains.
#define ROR4(N, x0, x1, x2, x3)                                                   \
    asm("s_nop 1\n\t"                                                             \
        "v_add_f32_dpp %0, %0, %0 row_ror:" #N " row_mask:0xf bank_mask:0xf\n\t"  \
        "v_add_f32_dpp %1, %1, %1 row_ror:" #N " row_mask:0xf bank_mask:0xf\n\t"  \
        "v_add_f32_dpp %2, %2, %2 row_ror:" #N " row_mask:0xf bank_mask:0xf\n\t"  \
        "v_add_f32_dpp %3, %3, %3 row_ror:" #N " row_mask:0xf bank_mask:0xf"      \
        : "+v"(x0), "+v"(x1), "+v"(x2), "+v"(x3))

// ---------- prep: qs = RoPE(q) * scale * log2e ----------
__global__ __launch_bounds__(128) void paged_attn_prep(
    const float* __restrict__ query,
    const int*   __restrict__ context_lens,
    float* __restrict__ qs)   // [NBKV][G*DHEAD]
{
    const int bkv = blockIdx.x;
    const int kv  = bkv & 7;
    const int b   = bkv >> 3;
    const int tid = threadIdx.x;

    __shared__ float s_cos[64], s_sin[64];
    const int pos = context_lens[b];
    if (tid < 64) {
        float invf = exp2f((float)tid * -0.20762050593046014f); // 10000^(-tid/64)
        float ang  = (float)pos * invf;
        s_cos[tid] = cosf(ang);
        s_sin[tid] = sinf(ang);
    }
    __syncthreads();

    // 1/sqrt(128) * log2(e): exp2 of the dot gives softmax weights
    const float scale = 0.08838834764831845f * 1.4426950408889634f;

    for (int idx = tid; idx < G * DHEAD; idx += 128) {
        int h = idx >> 7, d = idx & 127;
        const float* qp = query + ((size_t)b * HQ + kv * G + h) * DHEAD;
        float x = qp[d], r;
        if (d < 64) r = x * s_cos[d]      - qp[d + 64] * s_sin[d];
        else        r = x * s_cos[d - 64] + qp[d - 64] * s_sin[d - 64];
        qs[(size_t)bkv * (G * DHEAD) + idx] = r * scale;
    }
}

// ---------- main: one chunk of 256 positions per block ----------
__global__ __launch_bounds__(NT) void paged_attn_chunk(
    const float* __restrict__ k_cache,
    const float* __restrict__ v_cache,
    const int*   __restrict__ block_table,
    const int*   __restrict__ context_lens,
    const float* __restrict__ qs,
    float*       __restrict__ wsacc,   // [NSLOT][G*DHEAD]
    float*       __restrict__ wsl)     // [NSLOT][G]
{
    const int c   = blockIdx.x & (MAXCH - 1);
    const int bkv = blockIdx.x >> 3;
    const int kv  = bkv & 7;
    const int b   = bkv >> 3;

    const int pos = context_lens[b];
    const int c0  = c << 8;
    if (c0 > pos) return;              // chunk has no work (combine won't read it)

    const int tid  = threadIdx.x;
    const int w    = tid >> 6;
    const int lane = tid & 63;
    const int grp  = lane >> 4;
    const int sub  = lane & 15;

    __shared__ float s_wacc[NW][G][DHEAD];
    __shared__ float s_wl[NW][G];

    // q fragments (pre-roped, pre-scaled)
    v2f q2[G][4];
    const float* qb = qs + (size_t)bkv * (G * DHEAD) + sub * 8;
    #pragma unroll
    for (int h = 0; h < G; h++) {
        float4 qa = *(const float4*)(qb + h * DHEAD);
        float4 qc = *(const float4*)(qb + h * DHEAD + 4);
        q2[h][0] = v2f{qa.x, qa.y}; q2[h][1] = v2f{qa.z, qa.w};
        q2[h][2] = v2f{qc.x, qc.y}; q2[h][3] = v2f{qc.z, qc.w};
    }

    // the four cache blocks this wave touches -> SGPRs
    const int tb  = b * MAXB + (c0 >> 4) + w * 4;
    const int bt0 = __builtin_amdgcn_readfirstlane(block_table[tb + 0]);
    const int bt1 = __builtin_amdgcn_readfirstlane(block_table[tb + 1]);
    const int bt2 = __builtin_amdgcn_readfirstlane(block_table[tb + 2]);
    const int bt3 = __builtin_amdgcn_readfirstlane(block_table[tb + 3]);

    const size_t BLKF = (size_t)BS * HKV * DHEAD;   // floats per cache block
    const int loff = grp * (HKV * DHEAD) + kv * DHEAD + sub * 8;

    const float* kparr[4] = { k_cache + bt0 * BLKF + loff,
                              k_cache + bt1 * BLKF + loff,
                              k_cache + bt2 * BLKF + loff,
                              k_cache + bt3 * BLKF + loff };
    const float* vparr[4] = { v_cache + bt0 * BLKF + loff,
                              v_cache + bt1 * BLKF + loff,
                              v_cache + bt2 * BLKF + loff,
                              v_cache + bt3 * BLKF + loff };

    const int p0 = c0 + w * 64 + grp;  // position for it: p0 + it*4

    v2f acc2[G][4];
    float l[G];
    #pragma unroll
    for (int h = 0; h < G; h++) {
        l[h] = 0.f;
        #pragma unroll
        for (int j = 0; j < 4; j++) acc2[h][j] = v2f{0.f, 0.f};
    }

    float4 kaA, kbA, vaA, vbA;   // pipeline set A
    float4 kaB, kbB, vaB, vbB;   // pipeline set B

#define LOADSET(KA, KB, VA, VB, IT) do {                                       \
        const float* kp_ = kparr[(IT) >> 2] + ((IT) & 3) * (4 * HKV * DHEAD);  \
        const float* vp_ = vparr[(IT) >> 2] + ((IT) & 3) * (4 * HKV * DHEAD);  \
        KA = *(const float4*)kp_;  KB = *(const float4*)(kp_ + 4);             \
        VA = *(const float4*)vp_;  VB = *(const float4*)(vp_ + 4);             \
    } while (0)

#define COMPSET(KA, KB, VA, VB, IT) do {                                       \
        const int pi_ = p0 + (IT) * 4;                                         \
        v2f k0_ = v2f{KA.x, KA.y}, k1_ = v2f{KA.z, KA.w};                      \
        v2f k2_ = v2f{KB.x, KB.y}, k3_ = v2f{KB.z, KB.w};                      \
        v2f d0_ = pk_fma(q2[0][3], k3_, pk_fma(q2[0][2], k2_,                  \
                  pk_fma(q2[0][1], k1_, pk_mul(q2[0][0], k0_))));              \
        v2f d1_ = pk_fma(q2[1][3], k3_, pk_fma(q2[1][2], k2_,                  \
                  pk_fma(q2[1][1], k1_, pk_mul(q2[1][0], k0_))));              \
        v2f d2_ = pk_fma(q2[2][3], k3_, pk_fma(q2[2][2], k2_,                  \
                  pk_fma(q2[2][1], k1_, pk_mul(q2[2][0], k0_))));              \
        v2f d3_ = pk_fma(q2[3][3], k3_, pk_fma(q2[3][2], k2_,                  \
                  pk_fma(q2[3][1], k1_, pk_mul(q2[3][0], k0_))));              \
        float dt0 = d0_.x + d0_.y, dt1 = d1_.x + d1_.y;                        \
        float dt2 = d2_.x + d2_.y, dt3 = d3_.x + d3_.y;                        \
        ROR4(8, dt0, dt1, dt2, dt3);                                           \
        ROR4(4, dt0, dt1, dt2, dt3);                                           \
        ROR4(2, dt0, dt1, dt2, dt3);                                           \
        ROR4(1, dt0, dt1, dt2, dt3);                                           \
        const bool act_ = pi_ < pos;      /* pi_ == pos handled in combine */  \
        float wg0 = act_ ? fexp2(dt0) : 0.f;                                   \
        float wg1 = act_ ? fexp2(dt1) : 0.f;                                   \
        float wg2 = act_ ? fexp2(dt2) : 0.f;                                   \
        float wg3 = act_ ? fexp2(dt3) : 0.f;                                   \
        l[0] += wg0; l[1] += wg1; l[2] += wg2; l[3] += wg3;                    \
        v2f u0_ = v2f{VA.x, VA.y}, u1_ = v2f{VA.z, VA.w};                      \
        v2f u2_ = v2f{VB.x, VB.y}, u3_ = v2f{VB.z, VB.w};                      \
        v2f w0_ = v2f{wg0, wg0}, w1_ = v2f{wg1, wg1};                          \
        v2f w2_ = v2f{wg2, wg2}, w3_ = v2f{wg3, wg3};                          \
        acc2[0][0] = pk_fma(w0_, u0_, acc2[0][0]);                             \
        acc2[0][1] = pk_fma(w0_, u1_, acc2[0][1]);                             \
        acc2[0][2] = pk_fma(w0_, u2_, acc2[0][2]);                             \
        acc2[0][3] = pk_fma(w0_, u3_, acc2[0][3]);                             \
        acc2[1][0] = pk_fma(w1_, u0_, acc2[1][0]);                             \
        acc2[1][1] = pk_fma(w1_, u1_, acc2[1][1]);                             \
        acc2[1][2] = pk_fma(w1_, u2_, acc2[1][2]);                             \
        acc2[1][3] = pk_fma(w1_, u3_, acc2[1][3]);                             \
        acc2[2][0] = pk_fma(w2_, u0_, acc2[2][0]);                             \
        acc2[2][1] = pk_fma(w2_, u1_, acc2[2][1]);                             \
        acc2[2][2] = pk_fma(w2_, u2_, acc2[2][2]);                             \
        acc2[2][3] = pk_fma(w2_, u3_, acc2[2][3]);                             \
        acc2[3][0] = pk_fma(w3_, u0_, acc2[3][0]);                             \
        acc2[3][1] = pk_fma(w3_, u1_, acc2[3][1]);                             \
        acc2[3][2] = pk_fma(w3_, u2_, acc2[3][2]);                             \
        acc2[3][3] = pk_fma(w3_, u3_, acc2[3][3]);                             \
    } while (0)

    // depth-2 software pipeline over 16 compile-time iterations (64 positions)
    LOADSET(kaA, kbA, vaA, vbA, 0);
    LOADSET(kaB, kbB, vaB, vbB, 1);
    COMPSET(kaA, kbA, vaA, vbA, 0);   LOADSET(kaA, kbA, vaA, vbA, 2);
    COMPSET(kaB, kbB, vaB, vbB, 1);   LOADSET(kaB, kbB, vaB, vbB, 3);
    COMPSET(kaA, kbA, vaA, vbA, 2);   LOADSET(kaA, kbA, vaA, vbA, 4);
    COMPSET(kaB, kbB, vaB, vbB, 3);   LOADSET(kaB, kbB, vaB, vbB, 5);
    COMPSET(kaA, kbA, vaA, vbA, 4);   LOADSET(kaA, kbA, vaA, vbA, 6);
    COMPSET(kaB, kbB, vaB, vbB, 5);   LOADSET(kaB, kbB, vaB, vbB, 7);
    COMPSET(kaA, kbA, vaA, vbA, 6);   LOADSET(kaA, kbA, vaA, vbA, 8);
    COMPSET(kaB, kbB, vaB, vbB, 7);   LOADSET(kaB, kbB, vaB, vbB, 9);
    COMPSET(kaA, kbA, vaA, vbA, 8);   LOADSET(kaA, kbA, vaA, vbA, 10);
    COMPSET(kaB, kbB, vaB, vbB, 9);   LOADSET(kaB, kbB, vaB, vbB, 11);
    COMPSET(kaA, kbA, vaA, vbA, 10);  LOADSET(kaA, kbA, vaA, vbA, 12);
    COMPSET(kaB, kbB, vaB, vbB, 11);  LOADSET(kaB, kbB, vaB, vbB, 13);
    COMPSET(kaA, kbA, vaA, vbA, 12);  LOADSET(kaA, kbA, vaA, vbA, 14);
    COMPSET(kaB, kbB, vaB, vbB, 13);  LOADSET(kaB, kbB, vaB, vbB, 15);
    COMPSET(kaA, kbA, vaA, vbA, 14);
    COMPSET(kaB, kbB, vaB, vbB, 15);

#undef LOADSET
#undef COMPSET

    // ---- reduce across the 4 groups ----
    #pragma unroll
    for (int h = 0; h < G; h++) {
        l[h] += __shfl_xor(l[h], 16, 64);
        l[h] += __shfl_xor(l[h], 32, 64);
        #pragma unroll
        for (int j = 0; j < 4; j++) {
            float ax = acc2[h][j].x, ay = acc2[h][j].y;
            ax += __shfl_xor(ax, 16, 64); ax += __shfl_xor(ax, 32, 64);
            ay += __shfl_xor(ay, 16, 64); ay += __shfl_xor(ay, 32, 64);
            acc2[h][j] = v2f{ax, ay};
        }
    }
    if (lane < 16) {
        #pragma unroll
        for (int h = 0; h < G; h++)
            #pragma unroll
            for (int j = 0; j < 4; j++) {
                s_wacc[w][h][sub * 8 + 2 * j]     = acc2[h][j].x;
                s_wacc[w][h][sub * 8 + 2 * j + 1] = acc2[h][j].y;
            }
    }
    if (lane == 0) {
        #pragma unroll
        for (int h = 0; h < G; h++) s_wl[w][h] = l[h];
    }
    __syncthreads();

    const size_t slot_base = (size_t)blockIdx.x * (G * DHEAD);
    for (int idx = tid; idx < G * DHEAD; idx += NT) {
        float s = s_wacc[0][idx >> 7][idx & 127] + s_wacc[1][idx >> 7][idx & 127]
                + s_wacc[2][idx >> 7][idx & 127] + s_wacc[3][idx >> 7][idx & 127];
        wsacc[slot_base + idx] = s;
    }
    if (tid < G) {
        wsl[(size_t)blockIdx.x * G + tid] =
            s_wl[0][tid] + s_wl[1][tid] + s_wl[2][tid] + s_wl[3][tid];
    }
}

// ---------- combine: sum chunk partials + new-token contribution ----------
__global__ __launch_bounds__(512) void paged_attn_combine(
    const float* __restrict__ new_k,
    const float* __restrict__ new_v,
    const int*   __restrict__ context_lens,
    const float* __restrict__ qs,
    const float* __restrict__ wsacc,
    const float* __restrict__ wsl,
    float*       __restrict__ out)
{
    const int bkv = blockIdx.x;
    const int kv  = bkv & 7;
    const int b   = bkv >> 3;
    const int t   = threadIdx.x;
    const int h   = t >> 7;
    const int d   = t & 127;
    const int wv  = t >> 6;

    __shared__ float s_cos[64], s_sin[64], s_kn[DHEAD], s_ps[8];

    const int pos = context_lens[b];
    if (t < 64) {
        float invf = exp2f((float)t * -0.20762050593046014f);
        float ang  = (float)pos * invf;
        s_cos[t] = cosf(ang);
        s_sin[t] = sinf(ang);
    }
    __syncthreads();
    if (t < DHEAD) {
        const float* kp = new_k + ((size_t)b * HKV + kv) * DHEAD;
        float x = kp[t], r;
        if (t < 64) r = x * s_cos[t]      - kp[t + 64] * s_sin[t];
        else        r = x * s_cos[t - 64] + kp[t - 64] * s_sin[t - 64];
        s_kn[t] = r;
    }
    __syncthreads();

    // dot(q_hat[h], k_new) — q_hat already has scale*log2e folded in
    float part = qs[(size_t)bkv * (G * DHEAD) + t] * s_kn[d];
    #pragma unroll
    for (int off = 1; off < 64; off <<= 1) part += __shfl_xor(part, off, 64);
    if ((t & 63) == 0) s_ps[wv] = part;
    __syncthreads();

    const float wnew = fexp2(s_ps[2 * h] + s_ps[2 * h + 1]);

    const int len = pos + 1;
    const int nch = (len + CHUNK - 1) >> 8;

    float asum = 0.f, lsum = 0.f;
    for (int cc = 0; cc < nch; cc++) {
        asum += wsacc[((size_t)bkv * MAXCH + cc) * (G * DHEAD) + t];
        lsum += wsl[((size_t)bkv * MAXCH + cc) * G + h];
    }
    const float vnew = new_v[((size_t)b * HKV + kv) * DHEAD + d];
    out[((size_t)b * HQ + kv * G + h) * DHEAD + d] =
        (asum + wnew * vnew) / (lsum + wnew);
}

extern "C" void kernel_launch(void* const* d_in, const int* in_sizes, int n_in,
                              void* d_out, int out_size, void* d_ws, size_t ws_size,
                              hipStream_t stream) {
    const float* query        = (const float*)d_in[0];
    const float* new_k        = (const float*)d_in[1];
    const float* new_v        = (const float*)d_in[2];
    const float* k_cache      = (const float*)d_in[3];
    const float* v_cache      = (const float*)d_in[4];
    const int*   block_table  = (const int*)d_in[5];
    const int*   context_lens = (const int*)d_in[6];
    float* out = (float*)d_out;

    float* wsacc = (float*)d_ws;                          // NSLOT*512
    float* wsl   = wsacc + (size_t)NSLOT * G * DHEAD;     // NSLOT*4
    float* qs    = wsl + (size_t)NSLOT * G;               // NBKV*512

    paged_attn_prep<<<dim3(NBKV), dim3(128), 0, stream>>>(
        query, context_lens, qs);
    paged_attn_chunk<<<dim3(NSLOT), dim3(NT), 0, stream>>>(
        k_cache, v_cache, block_table, context_lens, qs, wsacc, wsl);
    paged_attn_combine<<<dim3(NBKV), dim3(512), 0, stream>>>(
        new_k, new_v, context_lens, qs, wsacc, wsl, out);
}